// Round 7
// baseline (324.880 us; speedup 1.0000x reference)
//
#include <hip/hip_runtime.h>

// Problem constants (fixed by the reference: shape (20,1,128,128,128) fp32)
#define NBATCH 20
#define ELEMS_PER_BATCH (128 * 128 * 128)       // 2,097,152
#define BLOCKS_PER_BATCH 64                     // 1280 blocks (R3 shape — measured best)
#define THREADS 256
#define BAT 4                                   // float4-pairs per pipeline batch
#define NSTEP 8                                 // BAT*NSTEP*THREADS*4 = 32768 elems/block * 64 = 2^21
#define NPART (NBATCH * BLOCKS_PER_BATCH)       // 1280 partials

#define LN2 0.69314718055994530942
// torch clamps log at -100 -> in log2 space: -100/ln2
#define LOG2_CLAMP (-144.26950408889634f)

// Native clang vector type (__builtin_nontemporal_load rejects HIP_vector_type).
typedef float f4 __attribute__((ext_vector_type(4)));

// Round-7: HYBRID cache policy. Evidence so far:
//   - cached both streams (R0/R1): 2.84 TB/s, FETCH = half (L3 serves ~168 MB)
//   - nt both streams (R3):        3.95 TB/s, all from HBM
//   - occupancy 20 vs 32 waves/CU: no effect on either path (R6)
// Theory: each service path plateaus independently of wave count. y alone
// (167.8 MB) fits in the 256 MB L3 and provably survives the harness fills
// (R0 showed 168 MB resident). So: x -> nt (pure HBM stream, no L3
// pollution), y -> normal cached (L3-resident steady state). If the HBM and
// L3 read paths serve concurrently, effective BW ~ 4 TB/s + L3 rate.
__device__ __forceinline__ void load_batch(const f4* __restrict__ x4,
                                           const f4* __restrict__ y4,
                                           long base, int tid,
                                           f4 (&bx)[BAT], f4 (&by)[BAT]) {
#pragma unroll
  for (int j = 0; j < BAT; ++j) {
    const long idx = base + (long)j * THREADS + tid;
    bx[j] = __builtin_nontemporal_load(&x4[idx]);  // x: HBM stream
    by[j] = y4[idx];                               // y: cached (L3-resident)
  }
}

__device__ __forceinline__ void compute_batch(const f4 (&bx)[BAT],
                                              const f4 (&by)[BAT],
                                              float& bce2, int& pc, int& tc) {
#pragma unroll
  for (int j = 0; j < BAT; ++j) {
#pragma unroll
    for (int c = 0; c < 4; ++c) {
      const float xx = bx[j][c];
      const float yy = by[j][c];
      // BCE in log2 space via hardware v_log_f32 (libm logf was VALU-bound).
      // log1p(-x) -> log2(1-x): exact for x>=0.5 (Sterbenz).
      const float lx = fmaxf(__builtin_amdgcn_logf(xx),        LOG2_CLAMP);
      const float l1 = fmaxf(__builtin_amdgcn_logf(1.0f - xx), LOG2_CLAMP);
      // y*lx + (1-y)*l1 = l1 + y*(lx - l1)
      bce2 += l1 + yy * (lx - l1);
      pc += (xx <= 0.5f);
      tc += (yy < 1.0f);
    }
  }
}

// Kernel 1: per-block partial reductions.
__global__ __launch_bounds__(THREADS) void partial_kernel(
    const float* __restrict__ x, const float* __restrict__ y,
    float* __restrict__ bce_part, int* __restrict__ pred_part,
    int* __restrict__ true_part) {
  const int b   = blockIdx.y;
  const int seg = blockIdx.x;
  const int tid = threadIdx.x;

  const long base4 = (long)b * (ELEMS_PER_BATCH / 4) +
                     (long)seg * (BAT * NSTEP * THREADS);
  const f4* __restrict__ x4 = (const f4*)x;
  const f4* __restrict__ y4 = (const f4*)y;

  float bce2 = 0.0f;  // sum in log2 units
  int pc = 0, tc = 0;

  f4 ax[BAT], ay[BAT], bx[BAT], by[BAT];
  load_batch(x4, y4, base4, tid, ax, ay);

  // Ping-pong register double-buffer; buffer selection compile-time (rule #20).
#define PIPE_STEP(CX, CY, NX, NY, S)                                           \
  if ((S) + 1 < NSTEP)                                                         \
    load_batch(x4, y4, base4 + (long)((S) + 1) * (BAT * THREADS), tid, NX, NY);\
  compute_batch(CX, CY, bce2, pc, tc);

  PIPE_STEP(ax, ay, bx, by, 0)
  PIPE_STEP(bx, by, ax, ay, 1)
  PIPE_STEP(ax, ay, bx, by, 2)
  PIPE_STEP(bx, by, ax, ay, 3)
  PIPE_STEP(ax, ay, bx, by, 4)
  PIPE_STEP(bx, by, ax, ay, 5)
  PIPE_STEP(ax, ay, bx, by, 6)
  PIPE_STEP(bx, by, ax, ay, 7)
#undef PIPE_STEP

  __shared__ float sb[THREADS];
  __shared__ int   sp[THREADS];
  __shared__ int   st[THREADS];
  sb[tid] = bce2; sp[tid] = pc; st[tid] = tc;
  __syncthreads();
#pragma unroll
  for (int s = THREADS / 2; s > 0; s >>= 1) {
    if (tid < s) {
      sb[tid] += sb[tid + s];
      sp[tid] += sp[tid + s];
      st[tid] += st[tid + s];
    }
    __syncthreads();
  }
  if (tid == 0) {
    const int o = b * BLOCKS_PER_BATCH + seg;
    bce_part[o]  = sb[0] * (float)LN2;  // back to natural-log units
    pred_part[o] = sp[0];
    true_part[o] = st[0];
  }
}

// Kernel 2: single block. Double-precision BCE total; per-batch POR; compose.
__global__ __launch_bounds__(THREADS) void final_kernel(
    const float* __restrict__ bce_part, const int* __restrict__ pred_part,
    const int* __restrict__ true_part, float* __restrict__ out) {
  const int tid = threadIdx.x;
  __shared__ double sred[THREADS];
  __shared__ float  spor[NBATCH];

  double local = 0.0;
  for (int i = tid; i < NPART; i += THREADS) local += (double)bce_part[i];
  sred[tid] = local;
  __syncthreads();
#pragma unroll
  for (int s = THREADS / 2; s > 0; s >>= 1) {
    if (tid < s) sred[tid] += sred[tid + s];
    __syncthreads();
  }

  if (tid < NBATCH) {
    int pc = 0, tc = 0;
    for (int k = 0; k < BLOCKS_PER_BATCH; ++k) {
      pc += pred_part[tid * BLOCKS_PER_BATCH + k];
      tc += true_part[tid * BLOCKS_PER_BATCH + k];
    }
    const float pp = (float)pc / (float)ELEMS_PER_BATCH;
    const float pt = (float)tc / (float)ELEMS_PER_BATCH;
    const float d = pp - pt;
    spor[tid] = d * d;
  }
  __syncthreads();

  if (tid == 0) {
    float pore_sum = 0.0f;
#pragma unroll
    for (int b = 0; b < NBATCH; ++b) pore_sum += spor[b];
    const float pore = pore_sum / (float)NBATCH;
    const double total = (double)NBATCH * (double)ELEMS_PER_BATCH;
    const float mse = (float)(-(sred[0] / total));
    out[0] = pore + mse;
    out[1] = pore;
  }
}

extern "C" void kernel_launch(void* const* d_in, const int* in_sizes, int n_in,
                              void* d_out, int out_size, void* d_ws, size_t ws_size,
                              hipStream_t stream) {
  const float* x = (const float*)d_in[0];
  const float* y = (const float*)d_in[1];
  float* out = (float*)d_out;

  // Workspace layout: [NPART floats][NPART ints][NPART ints] — every slot is
  // fully overwritten by partial_kernel, so no init needed despite 0xAA poison.
  float* bce_part  = (float*)d_ws;
  int*   pred_part = (int*)(bce_part + NPART);
  int*   true_part = pred_part + NPART;

  dim3 grid(BLOCKS_PER_BATCH, NBATCH);
  partial_kernel<<<grid, THREADS, 0, stream>>>(x, y, bce_part, pred_part, true_part);
  final_kernel<<<1, THREADS, 0, stream>>>(bce_part, pred_part, true_part, out);
}

// Round 8
// 307.894 us; speedup vs baseline: 1.0552x; 1.0552x over previous
//
#include <hip/hip_runtime.h>

// Problem constants (fixed by the reference: shape (20,1,128,128,128) fp32)
#define NBATCH 20
#define ELEMS_PER_BATCH (128 * 128 * 128)       // 2,097,152
#define BLOCKS_PER_BATCH 64                     // 1280 blocks, 5 blocks/CU, single round
#define THREADS 256
#define TILE_F4 512                             // f4 per tile per stream (= 2/thread)
#define NTILE 16                                // 16*512 = 8192 f4 per block per stream
#define NPART (NBATCH * BLOCKS_PER_BATCH)

#define LN2 0.69314718055994530942
#define LOG2_CLAMP (-144.26950408889634f)       // -100/ln2, torch's log clamp in log2 units

typedef float f4 __attribute__((ext_vector_type(4)));
typedef const __attribute__((address_space(1))) unsigned int gu32;
typedef __attribute__((address_space(3)))       unsigned int lu32;

// Round-8: direct-to-LDS DMA reads (global_load_lds, nt policy).
// Evidence: nt-VGPR reads plateau at 3.95 TB/s independent of occupancy
// (R3: 20 w/CU == R6: 32 w/CU); cached 2.84; hybrid 3.2 (worst of both —
// harness fills evict L3 between iterations). Model: read BW = per-CU
// outstanding-request capacity x 1KB / latency; the queue is per-CU (not
// per-wave), and nt wins because its service latency is shortest.
// global_load_lds returns to LDS instead of the VGPR line-fill path — if
// the VGPR-return queue is the cap, this breaks the 4 TB/s plateau.
// Each thread consumes only its own staged slots -> NO barriers; per-wave
// counted s_waitcnt vmcnt(4) only (never drain to 0 mid-loop).
__device__ __forceinline__ void stage16(const f4* g, f4* l) {
  // 16B/lane direct-to-LDS, aux=2 = NT (gfx940+ CPol: SC0=1, NT=2, SC1=16).
  // LDS dest is wave-uniform base + lane*16; our per-lane addrs are exactly
  // base+tid*16 contiguous, so the linear-dest requirement is satisfied.
  __builtin_amdgcn_global_load_lds((gu32*)g, (lu32*)l, 16, 0, 2);
}

__global__ __launch_bounds__(THREADS) void partial_kernel(
    const float* __restrict__ x, const float* __restrict__ y,
    float* __restrict__ bce_part, int* __restrict__ pred_part,
    int* __restrict__ true_part) {
  const int b   = blockIdx.y;
  const int seg = blockIdx.x;
  const int tid = threadIdx.x;

  const long base4 = (long)b * (ELEMS_PER_BATCH / 4) +
                     (long)seg * (NTILE * TILE_F4);
  const f4* __restrict__ x4 = (const f4*)x;
  const f4* __restrict__ y4 = (const f4*)y;

  // Exactly 32 KB: 2 buffers x (x-tile 8KB + y-tile 8KB). 160/32 = 5 blocks/CU.
  __shared__ f4 lx[2][TILE_F4];
  __shared__ f4 ly[2][TILE_F4];

  float bce2 = 0.0f;
  int pc = 0, tc = 0;

  // Stage tile T (4 DMA instructions: 2 x-f4 + 2 y-f4 per thread).
#define STAGE(T, B)                                                            \
  {                                                                            \
    const long tb = base4 + (long)(T) * TILE_F4;                               \
    stage16(&x4[tb + tid],       &lx[B][tid]);                                 \
    stage16(&x4[tb + 256 + tid], &lx[B][256 + tid]);                           \
    stage16(&y4[tb + tid],       &ly[B][tid]);                                 \
    stage16(&y4[tb + 256 + tid], &ly[B][256 + tid]);                           \
  }

  // Compute tile T from buffer B after waiting to <=VM outstanding DMAs.
  // "memory" clobber orders the ds_reads after the wait (they are memory ops;
  // rule-18's hoist hazard applies to register-only consumers). sched_barrier
  // pins scheduling as extra safety.
#define PH(T, B, VM)                                                           \
  asm volatile("s_waitcnt vmcnt(" #VM ")" ::: "memory");                       \
  __builtin_amdgcn_sched_barrier(0);                                           \
  {                                                                            \
    _Pragma("unroll")                                                          \
    for (int j = 0; j < 2; ++j) {                                              \
      const f4 xv = lx[B][j * 256 + tid];                                      \
      const f4 yv = ly[B][j * 256 + tid];                                      \
      _Pragma("unroll")                                                        \
      for (int c = 0; c < 4; ++c) {                                            \
        const float xx = xv[c];                                                \
        const float yy = yv[c];                                                \
        const float lg = fmaxf(__builtin_amdgcn_logf(xx),        LOG2_CLAMP);  \
        const float l1 = fmaxf(__builtin_amdgcn_logf(1.0f - xx), LOG2_CLAMP);  \
        bce2 += l1 + yy * (lg - l1); /* y*lx + (1-y)*l1 */                     \
        pc += (xx <= 0.5f);                                                    \
        tc += (yy < 1.0f);                                                     \
      }                                                                        \
    }                                                                          \
  }

  STAGE(0, 0)
  STAGE(1, 1)
  PH(0, 0, 4)  STAGE(2, 0)
  PH(1, 1, 4)  STAGE(3, 1)
  PH(2, 0, 4)  STAGE(4, 0)
  PH(3, 1, 4)  STAGE(5, 1)
  PH(4, 0, 4)  STAGE(6, 0)
  PH(5, 1, 4)  STAGE(7, 1)
  PH(6, 0, 4)  STAGE(8, 0)
  PH(7, 1, 4)  STAGE(9, 1)
  PH(8, 0, 4)  STAGE(10, 0)
  PH(9, 1, 4)  STAGE(11, 1)
  PH(10, 0, 4) STAGE(12, 0)
  PH(11, 1, 4) STAGE(13, 1)
  PH(12, 0, 4) STAGE(14, 0)
  PH(13, 1, 4) STAGE(15, 1)
  PH(14, 0, 4)
  PH(15, 1, 0)
#undef STAGE
#undef PH

  // Wave-level reduce (64 lanes), then 4 partials via reused LDS (keeps the
  // block at exactly 32 KB so 5 blocks/CU fit).
  float wb = bce2;
  int   wp = pc, wt = tc;
#pragma unroll
  for (int o = 32; o > 0; o >>= 1) {
    wb += __shfl_down(wb, o);
    wp += __shfl_down(wp, o);
    wt += __shfl_down(wt, o);
  }
  __syncthreads();  // all tile reads done; safe to reuse lx as scratch
  float* sb = (float*)&lx[0][0];
  int*   sp = (int*)&lx[1][0];
  int*   st = (int*)&ly[0][0];
  if ((tid & 63) == 0) {
    sb[tid >> 6] = wb;
    sp[tid >> 6] = wp;
    st[tid >> 6] = wt;
  }
  __syncthreads();
  if (tid == 0) {
    const float bsum = (sb[0] + sb[1]) + (sb[2] + sb[3]);
    const int o = b * BLOCKS_PER_BATCH + seg;
    bce_part[o]  = bsum * (float)LN2;  // back to natural-log units
    pred_part[o] = sp[0] + sp[1] + sp[2] + sp[3];
    true_part[o] = st[0] + st[1] + st[2] + st[3];
  }
}

// Kernel 2: single block. Double-precision BCE total; per-batch POR; compose.
__global__ __launch_bounds__(THREADS) void final_kernel(
    const float* __restrict__ bce_part, const int* __restrict__ pred_part,
    const int* __restrict__ true_part, float* __restrict__ out) {
  const int tid = threadIdx.x;
  __shared__ double sred[THREADS];
  __shared__ float  spor[NBATCH];

  double local = 0.0;
  for (int i = tid; i < NPART; i += THREADS) local += (double)bce_part[i];
  sred[tid] = local;
  __syncthreads();
#pragma unroll
  for (int s = THREADS / 2; s > 0; s >>= 1) {
    if (tid < s) sred[tid] += sred[tid + s];
    __syncthreads();
  }

  if (tid < NBATCH) {
    int pc = 0, tc = 0;
    for (int k = 0; k < BLOCKS_PER_BATCH; ++k) {
      pc += pred_part[tid * BLOCKS_PER_BATCH + k];
      tc += true_part[tid * BLOCKS_PER_BATCH + k];
    }
    const float pp = (float)pc / (float)ELEMS_PER_BATCH;
    const float pt = (float)tc / (float)ELEMS_PER_BATCH;
    const float d = pp - pt;
    spor[tid] = d * d;
  }
  __syncthreads();

  if (tid == 0) {
    float pore_sum = 0.0f;
#pragma unroll
    for (int b = 0; b < NBATCH; ++b) pore_sum += spor[b];
    const float pore = pore_sum / (float)NBATCH;
    const double total = (double)NBATCH * (double)ELEMS_PER_BATCH;
    const float mse = (float)(-(sred[0] / total));
    out[0] = pore + mse;
    out[1] = pore;
  }
}

extern "C" void kernel_launch(void* const* d_in, const int* in_sizes, int n_in,
                              void* d_out, int out_size, void* d_ws, size_t ws_size,
                              hipStream_t stream) {
  const float* x = (const float*)d_in[0];
  const float* y = (const float*)d_in[1];
  float* out = (float*)d_out;

  // Workspace layout: [NPART floats][NPART ints][NPART ints] — every slot is
  // fully overwritten by partial_kernel, so no init needed despite 0xAA poison.
  float* bce_part  = (float*)d_ws;
  int*   pred_part = (int*)(bce_part + NPART);
  int*   true_part = pred_part + NPART;

  dim3 grid(BLOCKS_PER_BATCH, NBATCH);
  partial_kernel<<<grid, THREADS, 0, stream>>>(x, y, bce_part, pred_part, true_part);
  final_kernel<<<1, THREADS, 0, stream>>>(bce_part, pred_part, true_part, out);
}